// Round 4
// baseline (374.641 us; speedup 1.0000x reference)
//
#include <hip/hip_runtime.h>
#include <stdint.h>

#define DI __device__ __forceinline__

using floatx4  = __attribute__((ext_vector_type(4)))  float;
using floatx16 = __attribute__((ext_vector_type(16))) float;
using short8   = __attribute__((ext_vector_type(8)))  short;   // 8 bf16 in 4 VGPRs

DI uint16_t f2b(float f) {  // fp32 -> bf16 round-to-nearest-even
  uint32_t u = __float_as_uint(f);
  return (uint16_t)((u + 0x7FFFu + ((u >> 16) & 1u)) >> 16);
}

DI void async_cp16(const uint16_t* g, uint16_t* l) {
  // 16B per lane, LDS dest = wave-uniform base + lane*16 (no padding allowed)
  __builtin_amdgcn_global_load_lds(
      (const __attribute__((address_space(1))) void*)g,
      (__attribute__((address_space(3))) void*)l, 16, 0, 0);
}

// ---------------------------------------------------------------- prep (ONE dispatch)
// blocks [0,512):   TT contraction T1t[lb][ijk] = sum_a g0[ij,a]*g1[a,(k,lb)]
//                   written DIRECTLY transposed (2B scatter; 8MB, L2/L3-absorbed)
//                   -> transpose kernel eliminated. blocks [0,16) also build g2t.
// blocks [512,2560): X fp32->bf16 grid-stride (independent of TT part; overlaps).
__global__ __launch_bounds__(256)
void prep(const float* __restrict__ x, uint16_t* __restrict__ Xbf,
          const float* __restrict__ g0, const float* __restrict__ g1,
          uint16_t* __restrict__ t1t,
          const float* __restrict__ g2, uint16_t* __restrict__ g2t) {
  const int bid = blockIdx.x;
  const int t = threadIdx.x;

  if (bid < 512) {
    __shared__ float g0s[64 * 64];    // [ij][a]   16KB
    __shared__ float g1s[64 * 128];   // [a][klb]  32KB
    const int bx = bid >> 7;          // 0..3   -> ij base
    const int by = bid & 127;         // 0..127 -> klb base
    const int rowbase = bx * 64;
    const int colbase = by * 128;

    if (bid < 16) {                   // g2t[(mn)][b] side-job: 16 blocks x 1024
      #pragma unroll
      for (int p = 0; p < 4; ++p) {
        int f = bid * 1024 + p * 256 + t;
        int mn = f >> 6, b = f & 63;
        g2t[f] = f2b(g2[b * 256 + mn]);
      }
    }
    for (int f = t; f < 4096; f += 256) g0s[f] = g0[rowbase * 64 + f];
    for (int f = t; f < 8192; f += 256) {
      int a = f >> 7, c = f & 127;
      g1s[f] = g1[(long)a * 16384 + colbase + c];
    }
    __syncthreads();

    const int tx = t & 31;
    const int ty = t >> 5;
    const int c0 = tx * 4;
    const int r0 = ty * 8;

    float acc[8][4];
    #pragma unroll
    for (int r = 0; r < 8; ++r)
      #pragma unroll
      for (int c = 0; c < 4; ++c) acc[r][c] = 0.f;

    for (int a4 = 0; a4 < 16; ++a4) {
      float g0r[8][4];
      #pragma unroll
      for (int r = 0; r < 8; ++r)
        *(float4*)&g0r[r][0] = *(const float4*)&g0s[(r0 + r) * 64 + a4 * 4];
      #pragma unroll
      for (int e = 0; e < 4; ++e) {
        float4 bv4 = *(const float4*)&g1s[(a4 * 4 + e) * 128 + c0];
        float bv[4] = {bv4.x, bv4.y, bv4.z, bv4.w};
        #pragma unroll
        for (int r = 0; r < 8; ++r)
          #pragma unroll
          for (int c = 0; c < 4; ++c)
            acc[r][c] += g0r[r][e] * bv[c];
      }
    }

    // write transposed: klb = colbase + c0 + c -> k fixed per block, lb varies
    const int k   = colbase >> 10;
    const int lb0 = (colbase & 1023) + c0;
    #pragma unroll
    for (int r = 0; r < 8; ++r)
      #pragma unroll
      for (int c = 0; c < 4; ++c)
        t1t[(long)(lb0 + c) * 4096 + (rowbase + r0 + r) * 16 + k] = f2b(acc[r][c]);
  } else {
    // ---- cvt role: 2048 blocks, 8 passes, 8 floats/thread/pass
    const int cb = bid - 512;
    for (int pass = 0; pass < 8; ++pass) {
      long i = (((long)pass * 2048 + cb) * 256 + t) * 8;
      float4 a = *(const float4*)(x + i);
      float4 b = *(const float4*)(x + i + 4);
      union { uint16_t u[8]; uint4 v; } o;
      o.u[0] = f2b(a.x); o.u[1] = f2b(a.y); o.u[2] = f2b(a.z); o.u[3] = f2b(a.w);
      o.u[4] = f2b(b.x); o.u[5] = f2b(b.y); o.u[6] = f2b(b.z); o.u[7] = f2b(b.w);
      *(uint4*)(Xbf + i) = o.v;
    }
  }
}

// ------------------------------------------------- fused V=Xbf@T1 then out=V@g2+bias
// R1 structure (1 barrier/K-tile, dbuf, 2 blocks/CU) + 32x32x16 MFMA:
//   2x FLOP/instruction (ubench 2382 vs 2075 TF), half the issue slots, same LDS
//   traffic (16x ds_read_b128 per K-tile). Per wave: 64x64 tile = 2x2 of 32x32,
//   16 MFMA per BK=64. C-layout (HW-verified): col=lane&31, row=(r&3)+8*(r>>2)+4*(lane>>5).
// XOR chunk-swizzle (involution, both sides): LDS stays linear for global_load_lds;
//   the GLOBAL source chunk is pre-swizzled; reads apply pos = c ^ ((row>>1)&3)
//   -> residual 4-way conflict (was 8/16-way), zero instruction cost.
// Phase 2 unchanged from R1 (16x16 frags vs g2t; Vs[128][136] padded, proven).
#define VSTRIDE 136

DI short8 ld_swz(const uint16_t* half, int row, int c) {
  // half: [128][32] shorts; chunk c in 0..3 (8 shorts each); pos = c ^ ((row>>1)&3)
  return *(const short8*)&half[row * 32 + ((c ^ ((row >> 1) & 3)) << 3)];
}

DI void stage_tile(const uint16_t* __restrict__ Ab, const uint16_t* __restrict__ Bb,
                   uint16_t* dstbuf, int k0, int wave, int srow, int schunk8) {
  // dstbuf (shorts): A[2][128][32] at [0,8192), B[2][128][32] at [8192,16384)
  #pragma unroll
  for (int ks = 0; ks < 2; ++ks)
    #pragma unroll
    for (int t = 0; t < 2; ++t) {
      const int rblk = wave * 2 + t;      // 16-row chunk, 1KB per cp16 issue
      async_cp16(Ab + (long)(rblk * 16 + srow) * 4096 + k0 + ks * 32 + schunk8,
                 dstbuf + ks * 4096 + rblk * 16 * 32);
      async_cp16(Bb + (long)(rblk * 16 + srow) * 4096 + k0 + ks * 32 + schunk8,
                 dstbuf + 8192 + ks * 4096 + rblk * 16 * 32);
    }
}

DI void compute_half32(const uint16_t* __restrict__ as_, const uint16_t* __restrict__ bs_,
                       int wm, int wn, int lane, floatx16 acc[2][2]) {
  const int r32 = lane & 31;
  const int ch  = lane >> 5;            // k-half within a 16-k step
  short8 af[2][2], bg[2][2];
  #pragma unroll
  for (int s = 0; s < 2; ++s) {         // two K=16 steps per 32-k half-buffer
    #pragma unroll
    for (int i = 0; i < 2; ++i)
      af[i][s] = ld_swz(as_, wm + i * 32 + r32, s * 2 + ch);
    #pragma unroll
    for (int j = 0; j < 2; ++j)
      bg[j][s] = ld_swz(bs_, wn + j * 32 + r32, s * 2 + ch);
  }
  #pragma unroll
  for (int s = 0; s < 2; ++s)
    #pragma unroll
    for (int i = 0; i < 2; ++i)
      #pragma unroll
      for (int j = 0; j < 2; ++j)
        acc[i][j] = __builtin_amdgcn_mfma_f32_32x32x16_bf16(af[i][s], bg[j][s], acc[i][j], 0, 0, 0);
}

__global__ __launch_bounds__(256, 2)
void gemm_fused(const uint16_t* __restrict__ A,    // Xbf 8192x4096
                const uint16_t* __restrict__ Bt,   // T1t 1024x4096 (k-contig)
                const uint16_t* __restrict__ g2t,  // 256x64 (k=b contig)
                const float* __restrict__ bias,
                float* __restrict__ out) {
  // 64KB LDS union: phase-1 dbuf (2 x 16384 shorts) / phase-2 Vs[128][VSTRIDE]
  __shared__ __align__(16) uint16_t lds[32768];
  uint16_t* buf0 = lds;
  uint16_t* buf1 = lds + 16384;

  const int bm = blockIdx.x * 128;
  const int tid  = threadIdx.x;
  const int wave = tid >> 6;
  const int lane = tid & 63;
  const int wm = (wave >> 1) * 64;
  const int wn = (wave & 1) * 64;

  const uint16_t* Ab = A + (long)bm * 4096;
  const uint16_t* Bb = Bt + (long)blockIdx.y * 128 * 4096;

  // staging: 16 rows x 4 chunks per 1KB issue; lane l -> (row l>>2, LDS chunk l&3)
  // LDS chunk p at row r must hold global chunk p^((r>>1)&3) => src chunk = (l&3)^((l>>3)&3)
  const int srow    = lane >> 2;
  const int schunk8 = (((lane & 3) ^ ((lane >> 3) & 3)) << 3);

  floatx16 acc[2][2];
  #pragma unroll
  for (int i = 0; i < 2; ++i)
    #pragma unroll
    for (int j = 0; j < 2; ++j)
      #pragma unroll
      for (int r = 0; r < 16; ++r) acc[i][j][r] = 0.f;

  // ---- pipelined K-loop: 64 tiles of BK=64, prefetch depth 1
  stage_tile(Ab, Bb, buf0, 0, wave, srow, schunk8);
  __syncthreads();

  for (int t = 0; t < 62; t += 2) {
    stage_tile(Ab, Bb, buf1, (t + 1) * 64, wave, srow, schunk8);
    compute_half32(buf0,        buf0 + 8192,  wm, wn, lane, acc);
    compute_half32(buf0 + 4096, buf0 + 12288, wm, wn, lane, acc);
    __syncthreads();

    stage_tile(Ab, Bb, buf0, (t + 2) * 64, wave, srow, schunk8);
    compute_half32(buf1,        buf1 + 8192,  wm, wn, lane, acc);
    compute_half32(buf1 + 4096, buf1 + 12288, wm, wn, lane, acc);
    __syncthreads();
  }
  stage_tile(Ab, Bb, buf1, 63 * 64, wave, srow, schunk8);
  compute_half32(buf0,        buf0 + 8192,  wm, wn, lane, acc);
  compute_half32(buf0 + 4096, buf0 + 12288, wm, wn, lane, acc);
  __syncthreads();
  compute_half32(buf1,        buf1 + 8192,  wm, wn, lane, acc);
  compute_half32(buf1 + 4096, buf1 + 12288, wm, wn, lane, acc);

  // ---- phase-1 epilogue: acc (32x32 C-layout) -> Vs bf16 [128][VSTRIDE]
  __syncthreads();                       // all waves' last ds_reads done (union safety)
  {
    const int cc = lane & 31;
    const int rh = (lane >> 5) * 4;
    #pragma unroll
    for (int i = 0; i < 2; ++i)
      #pragma unroll
      for (int j = 0; j < 2; ++j)
        #pragma unroll
        for (int r = 0; r < 16; ++r) {
          const int rr = (r & 3) + 8 * (r >> 2) + rh;
          lds[(wm + i * 32 + rr) * VSTRIDE + wn + j * 32 + cc] = f2b(acc[i][j][r]);
        }
  }
  __syncthreads();

  // ---- phase 2 (R1-proven): out[row][l*256+mn] = sum_b Vs[row][.]*g2t[mn][b] + bias
  const int fr = lane & 15;
  const int fk = (lane >> 4) * 8;
  const int colq = lane & 15;
  const int rowq = (lane >> 4) * 4;
  const int bsel   = (wave >> 1) * 64;
  const int mnBase = (wave & 1) * 128;
  const long ocol0 = (long)blockIdx.y * 512 + (wave >> 1) * 256 + mnBase;

  short8 bg2[8][2];
  #pragma unroll
  for (int jn = 0; jn < 8; ++jn)
    #pragma unroll
    for (int ks = 0; ks < 2; ++ks)
      bg2[jn][ks] = *(const short8*)&g2t[(mnBase + jn * 16 + fr) * 64 + ks * 32 + fk];

  float bvs[8];
  #pragma unroll
  for (int jn = 0; jn < 8; ++jn)
    bvs[jn] = bias[ocol0 + jn * 16 + colq];

  #pragma unroll
  for (int pass = 0; pass < 4; ++pass) {
    floatx4 acc2[2][8];
    #pragma unroll
    for (int im = 0; im < 2; ++im)
      #pragma unroll
      for (int jn = 0; jn < 8; ++jn)
        acc2[im][jn] = (floatx4){0.f, 0.f, 0.f, 0.f};

    short8 af2[2][2];
    #pragma unroll
    for (int im = 0; im < 2; ++im)
      #pragma unroll
      for (int ks = 0; ks < 2; ++ks)
        af2[im][ks] = *(const short8*)&lds[(pass * 32 + im * 16 + fr) * VSTRIDE + bsel + ks * 32 + fk];

    #pragma unroll
    for (int im = 0; im < 2; ++im)
      #pragma unroll
      for (int jn = 0; jn < 8; ++jn)
        #pragma unroll
        for (int ks = 0; ks < 2; ++ks)
          acc2[im][jn] = __builtin_amdgcn_mfma_f32_16x16x32_bf16(af2[im][ks], bg2[jn][ks], acc2[im][jn], 0, 0, 0);

    #pragma unroll
    for (int jn = 0; jn < 8; ++jn)
      #pragma unroll
      for (int im = 0; im < 2; ++im)
        #pragma unroll
        for (int r = 0; r < 4; ++r) {
          const int row = bm + pass * 32 + im * 16 + rowq + r;
          out[(long)row * 4096 + ocol0 + jn * 16 + colq] = acc2[im][jn][r] + bvs[jn];
        }
  }
}

// ---------------------------------------------------------------- launch
// ws layout (bytes): Xbf 64MB | T1t 8MB | g2t 32KB  (~72MB)
static constexpr long XBF_OFF = 0;
static constexpr long T1T_OFF = 67108864;
static constexpr long G2T_OFF = 75497472;

extern "C" void kernel_launch(void* const* d_in, const int* in_sizes, int n_in,
                              void* d_out, int out_size, void* d_ws, size_t ws_size,
                              hipStream_t stream) {
  const float* x    = (const float*)d_in[0];
  const float* g0   = (const float*)d_in[1];
  const float* g1   = (const float*)d_in[2];
  const float* g2   = (const float*)d_in[3];
  const float* bias = (const float*)d_in[4];
  float* out = (float*)d_out;

  char* ws = (char*)d_ws;
  uint16_t* Xbf = (uint16_t*)(ws + XBF_OFF);
  uint16_t* T1t = (uint16_t*)(ws + T1T_OFF);
  uint16_t* G2T = (uint16_t*)(ws + G2T_OFF);

  // 1) ONE prep dispatch: X->bf16 (grid-stride) || T1t direct-transposed || g2t
  prep<<<2560, 256, 0, stream>>>(x, Xbf, g0, g1, T1t, g2, G2T);
  // 2) fused: V = Xbf @ T1 (32x32x16 MFMA, dbuf) then out = V @ g2 + bias
  gemm_fused<<<dim3(64, 8), 256, 0, stream>>>(Xbf, T1t, G2T, bias, out);
}

// Round 5
// 367.455 us; speedup vs baseline: 1.0196x; 1.0196x over previous
//
#include <hip/hip_runtime.h>
#include <stdint.h>

#define DI __device__ __forceinline__

using floatx4  = __attribute__((ext_vector_type(4)))  float;
using floatx16 = __attribute__((ext_vector_type(16))) float;
using short8   = __attribute__((ext_vector_type(8)))  short;   // 8 bf16 in 4 VGPRs

DI uint16_t f2b(float f) {  // fp32 -> bf16 round-to-nearest-even
  uint32_t u = __float_as_uint(f);
  return (uint16_t)((u + 0x7FFFu + ((u >> 16) & 1u)) >> 16);
}

DI void async_cp16(const uint16_t* g, uint16_t* l) {
  // 16B per lane, LDS dest = wave-uniform base + lane*16 (no padding allowed)
  __builtin_amdgcn_global_load_lds(
      (const __attribute__((address_space(1))) void*)g,
      (__attribute__((address_space(3))) void*)l, 16, 0, 0);
}

// ---------------------------------------------------------------- X fp32->bf16
// LDS-free, 2048 blocks -> full occupancy (the R4 merge capped this at 3 blk/CU
// via the TT branch's 48KB static LDS — that was the 114us prep disaster).
__global__ __launch_bounds__(256)
void cvt_bf16(const float* __restrict__ x, uint16_t* __restrict__ y) {
  const int cb = blockIdx.x;
  const int t = threadIdx.x;
  for (int pass = 0; pass < 8; ++pass) {
    long i = (((long)pass * 2048 + cb) * 256 + t) * 8;
    float4 a = *(const float4*)(x + i);
    float4 b = *(const float4*)(x + i + 4);
    union { uint16_t u[8]; uint4 v; } o;
    o.u[0] = f2b(a.x); o.u[1] = f2b(a.y); o.u[2] = f2b(a.z); o.u[3] = f2b(a.w);
    o.u[4] = f2b(b.x); o.u[5] = f2b(b.y); o.u[6] = f2b(b.z); o.u[7] = f2b(b.w);
    *(uint4*)(y + i) = o.v;
  }
}

// ---------------------------------------------------------------- TT cores prep
// T1t[lb][ijk] = sum_a g0[ij,a]*g1[a,(k,lb)], written DIRECTLY transposed
// (2B scatter, 8MB, L2-absorbed — validated in R4, absmax unchanged).
// blocks [0,16) also build g2t[(mn)][b]. 512 blocks, ~10us.
__global__ __launch_bounds__(256)
void tt_prep(const float* __restrict__ g0, const float* __restrict__ g1,
             uint16_t* __restrict__ t1t,
             const float* __restrict__ g2, uint16_t* __restrict__ g2t) {
  __shared__ float g0s[64 * 64];    // [ij][a]   16KB
  __shared__ float g1s[64 * 128];   // [a][klb]  32KB
  const int bid = blockIdx.x;
  const int t = threadIdx.x;
  const int bx = bid >> 7;          // 0..3   -> ij base
  const int by = bid & 127;         // 0..127 -> klb base
  const int rowbase = bx * 64;
  const int colbase = by * 128;

  if (bid < 16) {                   // g2t side-job: 16 blocks x 1024 elems
    #pragma unroll
    for (int p = 0; p < 4; ++p) {
      int f = bid * 1024 + p * 256 + t;
      int mn = f >> 6, b = f & 63;
      g2t[f] = f2b(g2[b * 256 + mn]);
    }
  }
  for (int f = t; f < 4096; f += 256) g0s[f] = g0[rowbase * 64 + f];
  for (int f = t; f < 8192; f += 256) {
    int a = f >> 7, c = f & 127;
    g1s[f] = g1[(long)a * 16384 + colbase + c];
  }
  __syncthreads();

  const int tx = t & 31;
  const int ty = t >> 5;
  const int c0 = tx * 4;
  const int r0 = ty * 8;

  float acc[8][4];
  #pragma unroll
  for (int r = 0; r < 8; ++r)
    #pragma unroll
    for (int c = 0; c < 4; ++c) acc[r][c] = 0.f;

  for (int a4 = 0; a4 < 16; ++a4) {
    float g0r[8][4];
    #pragma unroll
    for (int r = 0; r < 8; ++r)
      *(float4*)&g0r[r][0] = *(const float4*)&g0s[(r0 + r) * 64 + a4 * 4];
    #pragma unroll
    for (int e = 0; e < 4; ++e) {
      float4 bv4 = *(const float4*)&g1s[(a4 * 4 + e) * 128 + c0];
      float bv[4] = {bv4.x, bv4.y, bv4.z, bv4.w};
      #pragma unroll
      for (int r = 0; r < 8; ++r)
        #pragma unroll
        for (int c = 0; c < 4; ++c)
          acc[r][c] += g0r[r][e] * bv[c];
    }
  }

  // write transposed: klb = colbase + c0 + c -> k fixed per block, lb varies
  const int k   = colbase >> 10;
  const int lb0 = (colbase & 1023) + c0;
  #pragma unroll
  for (int r = 0; r < 8; ++r)
    #pragma unroll
    for (int c = 0; c < 4; ++c)
      t1t[(long)(lb0 + c) * 4096 + (rowbase + r0 + r) * 16 + k] = f2b(acc[r][c]);
}

// ------------------------------------------------- fused V=Xbf@T1 then out=V@g2+bias
// R1 structure (1 barrier/K-tile, dbuf, 2 blocks/CU) + 32x32x16 MFMA:
//   2x FLOP/instruction (ubench 2382 vs 2075 TF), half the issue slots, same LDS
//   traffic. Per wave: 64x64 tile = 2x2 of 32x32, 16 MFMA per BK=64.
//   C-layout (HW-verified): col=lane&31, row=(r&3)+8*(r>>2)+4*(lane>>5).
// XOR chunk-swizzle (involution, both sides): LDS linear for global_load_lds;
//   GLOBAL source chunk pre-swizzled; reads apply pos = c ^ ((row>>1)&3).
// Phase 2 unchanged from R1 (16x16 frags vs g2t; Vs[128][136] padded, proven).
#define VSTRIDE 136

DI short8 ld_swz(const uint16_t* half, int row, int c) {
  // half: [128][32] shorts; chunk c in 0..3 (8 shorts each); pos = c ^ ((row>>1)&3)
  return *(const short8*)&half[row * 32 + ((c ^ ((row >> 1) & 3)) << 3)];
}

DI void stage_tile(const uint16_t* __restrict__ Ab, const uint16_t* __restrict__ Bb,
                   uint16_t* dstbuf, int k0, int wave, int srow, int schunk8) {
  // dstbuf (shorts): A[2][128][32] at [0,8192), B[2][128][32] at [8192,16384)
  #pragma unroll
  for (int ks = 0; ks < 2; ++ks)
    #pragma unroll
    for (int t = 0; t < 2; ++t) {
      const int rblk = wave * 2 + t;      // 16-row chunk, 1KB per cp16 issue
      async_cp16(Ab + (long)(rblk * 16 + srow) * 4096 + k0 + ks * 32 + schunk8,
                 dstbuf + ks * 4096 + rblk * 16 * 32);
      async_cp16(Bb + (long)(rblk * 16 + srow) * 4096 + k0 + ks * 32 + schunk8,
                 dstbuf + 8192 + ks * 4096 + rblk * 16 * 32);
    }
}

DI void compute_half32(const uint16_t* __restrict__ as_, const uint16_t* __restrict__ bs_,
                       int wm, int wn, int lane, floatx16 acc[2][2]) {
  const int r32 = lane & 31;
  const int ch  = lane >> 5;            // k-half within a 16-k step
  short8 af[2][2], bg[2][2];
  #pragma unroll
  for (int s = 0; s < 2; ++s) {         // two K=16 steps per 32-k half-buffer
    #pragma unroll
    for (int i = 0; i < 2; ++i)
      af[i][s] = ld_swz(as_, wm + i * 32 + r32, s * 2 + ch);
    #pragma unroll
    for (int j = 0; j < 2; ++j)
      bg[j][s] = ld_swz(bs_, wn + j * 32 + r32, s * 2 + ch);
  }
  #pragma unroll
  for (int s = 0; s < 2; ++s)
    #pragma unroll
    for (int i = 0; i < 2; ++i)
      #pragma unroll
      for (int j = 0; j < 2; ++j)
        acc[i][j] = __builtin_amdgcn_mfma_f32_32x32x16_bf16(af[i][s], bg[j][s], acc[i][j], 0, 0, 0);
}

__global__ __launch_bounds__(256, 2)
void gemm_fused(const uint16_t* __restrict__ A,    // Xbf 8192x4096
                const uint16_t* __restrict__ Bt,   // T1t 1024x4096 (k-contig)
                const uint16_t* __restrict__ g2t,  // 256x64 (k=b contig)
                const float* __restrict__ bias,
                float* __restrict__ out) {
  // 64KB LDS union: phase-1 dbuf (2 x 16384 shorts) / phase-2 Vs[128][VSTRIDE]
  __shared__ __align__(16) uint16_t lds[32768];
  uint16_t* buf0 = lds;
  uint16_t* buf1 = lds + 16384;

  const int bm = blockIdx.x * 128;
  const int tid  = threadIdx.x;
  const int wave = tid >> 6;
  const int lane = tid & 63;
  const int wm = (wave >> 1) * 64;
  const int wn = (wave & 1) * 64;

  const uint16_t* Ab = A + (long)bm * 4096;
  const uint16_t* Bb = Bt + (long)blockIdx.y * 128 * 4096;

  // staging: 16 rows x 4 chunks per 1KB issue; lane l -> (row l>>2, LDS chunk l&3)
  // LDS chunk p at row r holds global chunk p^((r>>1)&3) => src chunk = (l&3)^((l>>3)&3)
  const int srow    = lane >> 2;
  const int schunk8 = (((lane & 3) ^ ((lane >> 3) & 3)) << 3);

  floatx16 acc[2][2];
  #pragma unroll
  for (int i = 0; i < 2; ++i)
    #pragma unroll
    for (int j = 0; j < 2; ++j)
      #pragma unroll
      for (int r = 0; r < 16; ++r) acc[i][j][r] = 0.f;

  // ---- pipelined K-loop: 64 tiles of BK=64, prefetch depth 1
  stage_tile(Ab, Bb, buf0, 0, wave, srow, schunk8);
  __syncthreads();

  for (int t = 0; t < 62; t += 2) {
    stage_tile(Ab, Bb, buf1, (t + 1) * 64, wave, srow, schunk8);
    compute_half32(buf0,        buf0 + 8192,  wm, wn, lane, acc);
    compute_half32(buf0 + 4096, buf0 + 12288, wm, wn, lane, acc);
    __syncthreads();

    stage_tile(Ab, Bb, buf0, (t + 2) * 64, wave, srow, schunk8);
    compute_half32(buf1,        buf1 + 8192,  wm, wn, lane, acc);
    compute_half32(buf1 + 4096, buf1 + 12288, wm, wn, lane, acc);
    __syncthreads();
  }
  stage_tile(Ab, Bb, buf1, 63 * 64, wave, srow, schunk8);
  compute_half32(buf0,        buf0 + 8192,  wm, wn, lane, acc);
  compute_half32(buf0 + 4096, buf0 + 12288, wm, wn, lane, acc);
  __syncthreads();
  compute_half32(buf1,        buf1 + 8192,  wm, wn, lane, acc);
  compute_half32(buf1 + 4096, buf1 + 12288, wm, wn, lane, acc);

  // ---- phase-1 epilogue: acc (32x32 C-layout) -> Vs bf16 [128][VSTRIDE]
  __syncthreads();                       // all waves' last ds_reads done (union safety)
  {
    const int cc = lane & 31;
    const int rh = (lane >> 5) * 4;
    #pragma unroll
    for (int i = 0; i < 2; ++i)
      #pragma unroll
      for (int j = 0; j < 2; ++j)
        #pragma unroll
        for (int r = 0; r < 16; ++r) {
          const int rr = (r & 3) + 8 * (r >> 2) + rh;
          lds[(wm + i * 32 + rr) * VSTRIDE + wn + j * 32 + cc] = f2b(acc[i][j][r]);
        }
  }
  __syncthreads();

  // ---- phase 2 (R1-proven): out[row][l*256+mn] = sum_b Vs[row][.]*g2t[mn][b] + bias
  const int fr = lane & 15;
  const int fk = (lane >> 4) * 8;
  const int colq = lane & 15;
  const int rowq = (lane >> 4) * 4;
  const int bsel   = (wave >> 1) * 64;
  const int mnBase = (wave & 1) * 128;
  const long ocol0 = (long)blockIdx.y * 512 + (wave >> 1) * 256 + mnBase;

  short8 bg2[8][2];
  #pragma unroll
  for (int jn = 0; jn < 8; ++jn)
    #pragma unroll
    for (int ks = 0; ks < 2; ++ks)
      bg2[jn][ks] = *(const short8*)&g2t[(mnBase + jn * 16 + fr) * 64 + ks * 32 + fk];

  float bvs[8];
  #pragma unroll
  for (int jn = 0; jn < 8; ++jn)
    bvs[jn] = bias[ocol0 + jn * 16 + colq];

  #pragma unroll
  for (int pass = 0; pass < 4; ++pass) {
    floatx4 acc2[2][8];
    #pragma unroll
    for (int im = 0; im < 2; ++im)
      #pragma unroll
      for (int jn = 0; jn < 8; ++jn)
        acc2[im][jn] = (floatx4){0.f, 0.f, 0.f, 0.f};

    short8 af2[2][2];
    #pragma unroll
    for (int im = 0; im < 2; ++im)
      #pragma unroll
      for (int ks = 0; ks < 2; ++ks)
        af2[im][ks] = *(const short8*)&lds[(pass * 32 + im * 16 + fr) * VSTRIDE + bsel + ks * 32 + fk];

    #pragma unroll
    for (int im = 0; im < 2; ++im)
      #pragma unroll
      for (int jn = 0; jn < 8; ++jn)
        #pragma unroll
        for (int ks = 0; ks < 2; ++ks)
          acc2[im][jn] = __builtin_amdgcn_mfma_f32_16x16x32_bf16(af2[im][ks], bg2[jn][ks], acc2[im][jn], 0, 0, 0);

    #pragma unroll
    for (int jn = 0; jn < 8; ++jn)
      #pragma unroll
      for (int im = 0; im < 2; ++im)
        #pragma unroll
        for (int r = 0; r < 4; ++r) {
          const int row = bm + pass * 32 + im * 16 + rowq + r;
          out[(long)row * 4096 + ocol0 + jn * 16 + colq] = acc2[im][jn][r] + bvs[jn];
        }
  }
}

// ---------------------------------------------------------------- launch
// ws layout (bytes): Xbf 64MB | T1t 8MB | g2t 32KB  (~72MB)
static constexpr long XBF_OFF = 0;
static constexpr long T1T_OFF = 67108864;
static constexpr long G2T_OFF = 75497472;

extern "C" void kernel_launch(void* const* d_in, const int* in_sizes, int n_in,
                              void* d_out, int out_size, void* d_ws, size_t ws_size,
                              hipStream_t stream) {
  const float* x    = (const float*)d_in[0];
  const float* g0   = (const float*)d_in[1];
  const float* g1   = (const float*)d_in[2];
  const float* g2   = (const float*)d_in[3];
  const float* bias = (const float*)d_in[4];
  float* out = (float*)d_out;

  char* ws = (char*)d_ws;
  uint16_t* Xbf = (uint16_t*)(ws + XBF_OFF);
  uint16_t* T1t = (uint16_t*)(ws + T1T_OFF);
  uint16_t* G2T = (uint16_t*)(ws + G2T_OFF);

  // 1) X -> bf16 (LDS-free, full occupancy)
  cvt_bf16<<<2048, 256, 0, stream>>>(x, Xbf);
  // 2) T1t direct-transposed + g2t side-job (48KB LDS, 512 blocks, tiny)
  tt_prep<<<512, 256, 0, stream>>>(g0, g1, T1t, g2, G2T);
  // 3) fused: V = Xbf @ T1 (32x32x16 MFMA, dbuf) then out = V @ g2 + bias
  gemm_fused<<<dim3(64, 8), 256, 0, stream>>>(Xbf, T1t, G2T, bias, out);
}